// Round 1
// baseline (555.168 us; speedup 1.0000x reference)
//
#include <hip/hip_runtime.h>
#include <hip/hip_bf16.h>

#define N_NODES 50000
#define N_EDGES 800000
#define IN_DIM  100
#define HID     128
#define BN_EPS  1e-5f

// ---------------------------------------------------------------------------
// CSR build: histogram -> scan -> fill
// ---------------------------------------------------------------------------
__global__ void hist_kernel(const int* __restrict__ dst, int* __restrict__ deg) {
    int e = blockIdx.x * blockDim.x + threadIdx.x;
    if (e < N_EDGES) atomicAdd(&deg[dst[e]], 1);
}

// single-block scan over n elements; writes exclusive prefix to row_start[0..n]
// and a second copy to cursor[0..n-1] (used as insertion cursors by fill).
__global__ void scan_kernel(const int* __restrict__ deg, int* __restrict__ row_start,
                            int* __restrict__ cursor, int n) {
    __shared__ int wsum[16];
    int t = threadIdx.x;          // 1024 threads
    int lane = t & 63, wv = t >> 6;
    int carry = 0;                // identical in every thread
    for (int base = 0; base < n; base += 1024) {
        int i = base + t;
        int v = (i < n) ? deg[i] : 0;
        // wave-inclusive scan
        int s = v;
        #pragma unroll
        for (int off = 1; off < 64; off <<= 1) {
            int u = __shfl_up(s, off, 64);
            if (lane >= off) s += u;
        }
        if (lane == 63) wsum[wv] = s;
        __syncthreads();
        if (wv == 0) {
            int w = (lane < 16) ? wsum[lane] : 0;
            #pragma unroll
            for (int off = 1; off < 16; off <<= 1) {
                int u = __shfl_up(w, off, 64);
                if (lane >= off) w += u;
            }
            if (lane < 16) wsum[lane] = w;
        }
        __syncthreads();
        int waveoff = (wv == 0) ? 0 : wsum[wv - 1];
        int excl = s - v + waveoff + carry;
        if (i < n) { row_start[i] = excl; cursor[i] = excl; }
        carry += wsum[15];
        __syncthreads();
    }
    if (t == 0) row_start[n] = carry;
}

__global__ void fill_kernel(const int* __restrict__ src, const int* __restrict__ dst,
                            int* __restrict__ cursor, int* __restrict__ ssrc) {
    int e = blockIdx.x * blockDim.x + threadIdx.x;
    if (e < N_EDGES) {
        int pos = atomicAdd(&cursor[dst[e]], 1);
        ssrc[pos] = src[e];
    }
}

// ---------------------------------------------------------------------------
// Mean aggregation: one wave per node, lanes hold features f and f+64
// ---------------------------------------------------------------------------
template <int D>
__global__ void agg_kernel(const int* __restrict__ ssrc, const int* __restrict__ rs,
                           const float* __restrict__ X, float* __restrict__ out) {
    int node = (blockIdx.x * blockDim.x + threadIdx.x) >> 6;
    if (node >= N_NODES) return;
    int lane = threadIdx.x & 63;
    int beg = rs[node], end = rs[node + 1];
    float a0 = 0.f, a1 = 0.f;
    int e = beg;
    for (; e + 1 < end; e += 2) {
        int s0 = ssrc[e], s1 = ssrc[e + 1];
        const float* r0 = X + (size_t)s0 * D;
        const float* r1 = X + (size_t)s1 * D;
        float v00 = r0[lane];
        float v10 = r1[lane];
        float v01 = (lane + 64 < D) ? r0[lane + 64] : 0.f;
        float v11 = (lane + 64 < D) ? r1[lane + 64] : 0.f;
        a0 += v00 + v10;
        a1 += v01 + v11;
    }
    if (e < end) {
        int s0 = ssrc[e];
        const float* r0 = X + (size_t)s0 * D;
        a0 += r0[lane];
        if (lane + 64 < D) a1 += r0[lane + 64];
    }
    float inv = 1.0f / fmaxf((float)(end - beg), 1.0f);
    out[(size_t)node * D + lane] = a0 * inv;
    if (lane + 64 < D) out[(size_t)node * D + lane + 64] = a1 * inv;
}

// ---------------------------------------------------------------------------
// Dual-input GEMM: out[M x 128] = A1[M x K1] @ W1[K1 x 128]
//                               + A2[M x K2] @ W2[K2 x 128] + bias
// fp32 vector-ALU (no fp32 MFMA on CDNA4). 64-row x 128-col tile per block.
// ---------------------------------------------------------------------------
#define BM 64
#define KT 32

__global__ __launch_bounds__(256) void gemm_dual(
    const float* __restrict__ A1, int K1,
    const float* __restrict__ A2, int K2,
    const float* __restrict__ W1, const float* __restrict__ W2,
    const float* __restrict__ bias, float* __restrict__ out, int M) {
    __shared__ float As[KT][BM + 4];   // +4 pad keeps 16B alignment, breaks stride
    __shared__ float Ws[KT][128];
    int tid = threadIdx.x;
    int tx = tid & 31;   // col group: cols tx*4 .. tx*4+3
    int ty = tid >> 5;   // row group: rows ty*8 .. ty*8+7
    int row0 = blockIdx.x * BM;

    float acc[8][4];
    #pragma unroll
    for (int i = 0; i < 8; i++)
        #pragma unroll
        for (int j = 0; j < 4; j++) acc[i][j] = 0.f;

    for (int phase = 0; phase < 2; ++phase) {
        const float* A = phase ? A2 : A1;
        const float* W = phase ? W2 : W1;
        int K = phase ? K2 : K1;
        for (int k0 = 0; k0 < K; k0 += KT) {
            __syncthreads();
            // stage A (transposed): 64 rows x 32 k
            #pragma unroll
            for (int l = 0; l < 2; ++l) {
                int lin = tid + l * 256;      // 0..511 float4 slots
                int r = lin >> 3;             // 0..63
                int kg = lin & 7;             // k-group of 4
                int grow = row0 + r;
                int k = k0 + kg * 4;
                float4 v = make_float4(0.f, 0.f, 0.f, 0.f);
                if (grow < M) {
                    if (k + 3 < K) {
                        v = *(const float4*)(A + (size_t)grow * K + k);
                    } else {
                        float tmp[4] = {0.f, 0.f, 0.f, 0.f};
                        #pragma unroll
                        for (int j = 0; j < 4; j++)
                            if (k + j < K) tmp[j] = A[(size_t)grow * K + k + j];
                        v = make_float4(tmp[0], tmp[1], tmp[2], tmp[3]);
                    }
                }
                As[kg * 4 + 0][r] = v.x;
                As[kg * 4 + 1][r] = v.y;
                As[kg * 4 + 2][r] = v.z;
                As[kg * 4 + 3][r] = v.w;
            }
            // stage W: 32 k x 128 cols
            #pragma unroll
            for (int l = 0; l < 4; ++l) {
                int lin = tid + l * 256;      // 0..1023 float4 slots
                int kk = lin >> 5;            // 0..31
                int cg = lin & 31;            // col group
                float4 v = make_float4(0.f, 0.f, 0.f, 0.f);
                if (k0 + kk < K)
                    v = *(const float4*)(W + (size_t)(k0 + kk) * 128 + cg * 4);
                *(float4*)&Ws[kk][cg * 4] = v;
            }
            __syncthreads();
            #pragma unroll
            for (int kk = 0; kk < KT; ++kk) {
                float4 w = *(const float4*)&Ws[kk][tx * 4];
                float4 a0 = *(const float4*)&As[kk][ty * 8];
                float4 a1 = *(const float4*)&As[kk][ty * 8 + 4];
                float a[8] = {a0.x, a0.y, a0.z, a0.w, a1.x, a1.y, a1.z, a1.w};
                #pragma unroll
                for (int i = 0; i < 8; i++) {
                    acc[i][0] = fmaf(a[i], w.x, acc[i][0]);
                    acc[i][1] = fmaf(a[i], w.y, acc[i][1]);
                    acc[i][2] = fmaf(a[i], w.z, acc[i][2]);
                    acc[i][3] = fmaf(a[i], w.w, acc[i][3]);
                }
            }
        }
    }
    float4 b = *(const float4*)&bias[tx * 4];
    #pragma unroll
    for (int i = 0; i < 8; i++) {
        int r = row0 + ty * 8 + i;
        if (r < M) {
            float4 v = make_float4(acc[i][0] + b.x, acc[i][1] + b.y,
                                   acc[i][2] + b.z, acc[i][3] + b.w);
            *(float4*)(out + (size_t)r * 128 + tx * 4) = v;
        }
    }
}

// ---------------------------------------------------------------------------
// BatchNorm: column sums/sumsq -> scale/shift -> apply (+ optional ReLU)
// ---------------------------------------------------------------------------
__global__ void stats_kernel(const float* __restrict__ h, float* __restrict__ stats, int M) {
    __shared__ float l1[256], l2[256];
    int t = threadIdx.x;
    int f = t & 127;
    int part = t >> 7;
    float s1 = 0.f, s2 = 0.f;
    for (int n = blockIdx.x * 2 + part; n < M; n += gridDim.x * 2) {
        float v = h[(size_t)n * 128 + f];
        s1 += v;
        s2 = fmaf(v, v, s2);
    }
    l1[t] = s1; l2[t] = s2;
    __syncthreads();
    if (t < 128) {
        atomicAdd(&stats[f], l1[t] + l1[t + 128]);
        atomicAdd(&stats[128 + f], l2[t] + l2[t + 128]);
    }
}

__global__ void finalize_kernel(const float* __restrict__ stats,
                                const float* __restrict__ gamma,
                                const float* __restrict__ beta,
                                float* __restrict__ ss, float inv_n) {
    int t = threadIdx.x;  // 128
    float mean = stats[t] * inv_n;
    float var = stats[128 + t] * inv_n - mean * mean;
    float inv = 1.0f / sqrtf(var + BN_EPS);
    float sc = gamma[t] * inv;
    ss[t] = sc;
    ss[128 + t] = beta[t] - mean * sc;
}

template <int RELU>
__global__ void bn_apply_kernel(float* __restrict__ h, const float* __restrict__ ss, int total4) {
    int i = blockIdx.x * blockDim.x + threadIdx.x;
    if (i >= total4) return;
    int cg = i & 31;  // float4 col group within 128-wide row
    float4 v = ((float4*)h)[i];
    float4 sc = *(const float4*)&ss[cg * 4];
    float4 sh = *(const float4*)&ss[128 + cg * 4];
    v.x = fmaf(v.x, sc.x, sh.x);
    v.y = fmaf(v.y, sc.y, sh.y);
    v.z = fmaf(v.z, sc.z, sh.z);
    v.w = fmaf(v.w, sc.w, sh.w);
    if (RELU) {
        v.x = fmaxf(v.x, 0.f);
        v.y = fmaxf(v.y, 0.f);
        v.z = fmaxf(v.z, 0.f);
        v.w = fmaxf(v.w, 0.f);
    }
    ((float4*)h)[i] = v;
}

// ---------------------------------------------------------------------------
extern "C" void kernel_launch(void* const* d_in, const int* in_sizes, int n_in,
                              void* d_out, int out_size, void* d_ws, size_t ws_size,
                              hipStream_t stream) {
    const float* x      = (const float*)d_in[0];
    const int*   ei     = (const int*)d_in[1];
    const float* W_l0   = (const float*)d_in[2];
    const float* b_l0   = (const float*)d_in[3];
    const float* W_r0   = (const float*)d_in[4];
    const float* gamma0 = (const float*)d_in[5];
    const float* beta0  = (const float*)d_in[6];
    const float* W_l1   = (const float*)d_in[7];
    const float* b_l1   = (const float*)d_in[8];
    const float* W_r1   = (const float*)d_in[9];
    const float* gamma1 = (const float*)d_in[10];
    const float* beta1  = (const float*)d_in[11];

    const int* src = ei;
    const int* dst = ei + N_EDGES;

    // carve workspace
    char* w = (char*)d_ws;
    auto alloc = [&](size_t bytes) {
        void* p = (void*)w;
        w += (bytes + 255) & ~(size_t)255;
        return p;
    };
    int*   deg       = (int*)alloc(sizeof(int) * N_NODES);
    int*   row_start = (int*)alloc(sizeof(int) * (N_NODES + 1));
    int*   cursor    = (int*)alloc(sizeof(int) * N_NODES);
    int*   ssrc      = (int*)alloc(sizeof(int) * N_EDGES);
    float* agg       = (float*)alloc(sizeof(float) * (size_t)N_NODES * HID);
    float* h         = (float*)alloc(sizeof(float) * (size_t)N_NODES * HID);
    float* stats0    = (float*)alloc(sizeof(float) * 256);
    float* ss0       = (float*)alloc(sizeof(float) * 256);
    float* stats1    = (float*)alloc(sizeof(float) * 256);
    float* ss1       = (float*)alloc(sizeof(float) * 256);
    float* outp      = (float*)d_out;

    hipMemsetAsync(deg, 0, sizeof(int) * N_NODES, stream);
    hipMemsetAsync(stats0, 0, sizeof(float) * 256, stream);
    hipMemsetAsync(stats1, 0, sizeof(float) * 256, stream);

    const int EB = (N_EDGES + 255) / 256;
    const float inv_n = 1.0f / (float)N_NODES;
    const int total4 = N_NODES * HID / 4;

    // CSR build
    hist_kernel<<<EB, 256, 0, stream>>>(dst, deg);
    scan_kernel<<<1, 1024, 0, stream>>>(deg, row_start, cursor, N_NODES);
    fill_kernel<<<EB, 256, 0, stream>>>(src, dst, cursor, ssrc);

    // Layer 0
    agg_kernel<IN_DIM><<<(N_NODES + 3) / 4, 256, 0, stream>>>(ssrc, row_start, x, agg);
    gemm_dual<<<(N_NODES + BM - 1) / BM, 256, 0, stream>>>(agg, IN_DIM, x, IN_DIM,
                                                           W_l0, W_r0, b_l0, h, N_NODES);
    stats_kernel<<<256, 256, 0, stream>>>(h, stats0, N_NODES);
    finalize_kernel<<<1, 128, 0, stream>>>(stats0, gamma0, beta0, ss0, inv_n);
    bn_apply_kernel<1><<<(total4 + 255) / 256, 256, 0, stream>>>(h, ss0, total4);

    // Layer 1
    agg_kernel<HID><<<(N_NODES + 3) / 4, 256, 0, stream>>>(ssrc, row_start, h, agg);
    gemm_dual<<<(N_NODES + BM - 1) / BM, 256, 0, stream>>>(agg, HID, h, HID,
                                                           W_l1, W_r1, b_l1, outp, N_NODES);
    stats_kernel<<<256, 256, 0, stream>>>(outp, stats1, N_NODES);
    finalize_kernel<<<1, 128, 0, stream>>>(stats1, gamma1, beta1, ss1, inv_n);
    bn_apply_kernel<0><<<(total4 + 255) / 256, 256, 0, stream>>>(outp, ss1, total4);
}

// Round 2
// 433.917 us; speedup vs baseline: 1.2794x; 1.2794x over previous
//
#include <hip/hip_runtime.h>
#include <hip/hip_bf16.h>

#define N_NODES 50000
#define N_EDGES 800000
#define NPAD    50048          // 782 * 64, so GEMM A-staging never reads OOB
#define IN_DIM  100
#define HID     128
#define BN_EPS  1e-5f

typedef unsigned int uint;
typedef unsigned short u16;
typedef __attribute__((ext_vector_type(8))) unsigned short us8;
typedef __attribute__((ext_vector_type(8))) short s8;      // bf16 MFMA frag (guide-verified)
typedef __attribute__((ext_vector_type(4))) float f4;

__device__ __forceinline__ u16 f2bf(float f) {
    uint u = __builtin_bit_cast(uint, f);
    uint r = (u + 0x7FFFu + ((u >> 16) & 1u)) >> 16;   // RNE
    return (u16)r;
}
__device__ __forceinline__ float bflo(uint p) { return __builtin_bit_cast(float, p << 16); }
__device__ __forceinline__ float bfhi(uint p) { return __builtin_bit_cast(float, p & 0xFFFF0000u); }

// ---------------------------------------------------------------------------
// CSR build: histogram -> scan -> fill
// ---------------------------------------------------------------------------
__global__ void hist_kernel(const int* __restrict__ dst, int* __restrict__ deg) {
    int e = blockIdx.x * blockDim.x + threadIdx.x;
    if (e < N_EDGES) atomicAdd(&deg[dst[e]], 1);
}

__global__ void scan_kernel(const int* __restrict__ deg, int* __restrict__ row_start,
                            int* __restrict__ cursor, int n) {
    __shared__ int wsum[16];
    int t = threadIdx.x;          // 1024 threads
    int lane = t & 63, wv = t >> 6;
    int carry = 0;
    for (int base = 0; base < n; base += 1024) {
        int i = base + t;
        int v = (i < n) ? deg[i] : 0;
        int s = v;
        #pragma unroll
        for (int off = 1; off < 64; off <<= 1) {
            int u = __shfl_up(s, off, 64);
            if (lane >= off) s += u;
        }
        if (lane == 63) wsum[wv] = s;
        __syncthreads();
        if (wv == 0) {
            int w = (lane < 16) ? wsum[lane] : 0;
            #pragma unroll
            for (int off = 1; off < 16; off <<= 1) {
                int u = __shfl_up(w, off, 64);
                if (lane >= off) w += u;
            }
            if (lane < 16) wsum[lane] = w;
        }
        __syncthreads();
        int waveoff = (wv == 0) ? 0 : wsum[wv - 1];
        int excl = s - v + waveoff + carry;
        if (i < n) { row_start[i] = excl; cursor[i] = excl; }
        carry += wsum[15];
        __syncthreads();
    }
    if (t == 0) row_start[n] = carry;
}

__global__ void fill_kernel(const int* __restrict__ src, const int* __restrict__ dst,
                            int* __restrict__ cursor, int* __restrict__ ssrc) {
    int e = blockIdx.x * blockDim.x + threadIdx.x;
    if (e < N_EDGES) {
        int pos = atomicAdd(&cursor[dst[e]], 1);
        ssrc[pos] = src[e];
    }
}

// ---------------------------------------------------------------------------
// Casts to bf16
// ---------------------------------------------------------------------------
__global__ void cast_x_kernel(const float* __restrict__ x, u16* __restrict__ xb) {
    int idx = blockIdx.x * blockDim.x + threadIdx.x;
    if (idx >= N_NODES * 128) return;
    int row = idx >> 7, k = idx & 127;
    float v = (k < IN_DIM) ? x[row * IN_DIM + k] : 0.f;
    xb[idx] = f2bf(v);
}

// weights: fp32 [Ksrc][128] -> bf16 transposed [128 n][128 k], zero-padded k
__global__ void cast_w_kernel(const float* __restrict__ W_l0, const float* __restrict__ W_r0,
                              const float* __restrict__ W_l1, const float* __restrict__ W_r1,
                              u16* __restrict__ d) {
    int w = blockIdx.y;
    const float* s = (w == 0) ? W_l0 : (w == 1) ? W_r0 : (w == 2) ? W_l1 : W_r1;
    int Ks = (w < 2) ? IN_DIM : HID;
    int idx = blockIdx.x * 256 + threadIdx.x;   // 0..16383
    int n = idx >> 7, k = idx & 127;
    float v = (k < Ks) ? s[k * 128 + n] : 0.f;
    d[w * 16384 + idx] = f2bf(v);
}

// ---------------------------------------------------------------------------
// Mean aggregation over bf16 rows (128 wide): one wave per node
// ---------------------------------------------------------------------------
__global__ void agg_bf16(const int* __restrict__ ssrc, const int* __restrict__ rs,
                         const u16* __restrict__ X, u16* __restrict__ out) {
    int node = (blockIdx.x * blockDim.x + threadIdx.x) >> 6;
    if (node >= N_NODES) return;
    int lane = threadIdx.x & 63;
    int beg = rs[node], end = rs[node + 1];
    float a0 = 0.f, a1 = 0.f;
    int e = beg;
    for (; e + 1 < end; e += 2) {
        const uint* r0 = (const uint*)(X + (size_t)ssrc[e] * 128);
        const uint* r1 = (const uint*)(X + (size_t)ssrc[e + 1] * 128);
        uint p0 = r0[lane];
        uint p1 = r1[lane];
        a0 += bflo(p0) + bflo(p1);
        a1 += bfhi(p0) + bfhi(p1);
    }
    if (e < end) {
        uint p0 = ((const uint*)(X + (size_t)ssrc[e] * 128))[lane];
        a0 += bflo(p0);
        a1 += bfhi(p0);
    }
    float inv = 1.0f / fmaxf((float)(end - beg), 1.0f);
    ((uint*)(out + (size_t)node * 128))[lane] =
        (uint)f2bf(a0 * inv) | ((uint)f2bf(a1 * inv) << 16);
}

// ---------------------------------------------------------------------------
// Dual-input bf16 MFMA GEMM:
//   out[M x 128] = A1 @ Wt1^T + A2 @ Wt2^T + bias   (fp32 out)
// A1,A2: bf16 [NPAD][128] row-major. Wt: bf16 [128 n][128 k] (pre-transposed).
// Block = 256 thr (4 waves), tile 64 rows x 128 cols; wave -> 32x64 quadrant.
// ---------------------------------------------------------------------------
__global__ __launch_bounds__(256) void gemm_mfma(
    const u16* __restrict__ A1, const u16* __restrict__ A2,
    const u16* __restrict__ Wt1, const u16* __restrict__ Wt2,
    const float* __restrict__ bias, float* __restrict__ out, int M) {
    __shared__ u16 Als[64][32];
    __shared__ u16 Bls[128][32];

    int tid = threadIdx.x;
    int wave = tid >> 6;
    int lane = tid & 63;
    int l16 = lane & 15;
    int quad = lane >> 4;
    int rm = (wave & 1) * 32;       // row quadrant within tile
    int cn = (wave >> 1) * 64;      // col quadrant
    int row0 = blockIdx.x * 64;

    f4 acc[2][4];
    #pragma unroll
    for (int i = 0; i < 2; i++)
        #pragma unroll
        for (int j = 0; j < 4; j++)
            acc[i][j] = (f4)0.f;

    #pragma unroll
    for (int phase = 0; phase < 2; ++phase) {
        const u16* A  = phase ? A2 : A1;
        const u16* Wt = phase ? Wt2 : Wt1;
        #pragma unroll
        for (int k0 = 0; k0 < 128; k0 += 32) {
            __syncthreads();
            // stage A: 64 rows x 32 k (each thread one 16B chunk)
            {
                int r = tid >> 2, c = tid & 3;
                us8 v = *(const us8*)(A + (size_t)(row0 + r) * 128 + k0 + c * 8);
                *(us8*)&Als[r][c * 8] = v;
            }
            // stage B: 128 n x 32 k (straight copy from pre-transposed Wt)
            #pragma unroll
            for (int rep = 0; rep < 2; ++rep) {
                int idx = rep * 256 + tid;
                int n = idx >> 2, c = idx & 3;
                us8 v = *(const us8*)(Wt + n * 128 + k0 + c * 8);
                *(us8*)&Bls[n][c * 8] = v;
            }
            __syncthreads();
            // fragments + MFMA
            s8 af[2], bfr[4];
            #pragma unroll
            for (int mt = 0; mt < 2; ++mt)
                af[mt] = *(const s8*)&Als[rm + mt * 16 + l16][quad * 8];
            #pragma unroll
            for (int nt = 0; nt < 4; ++nt)
                bfr[nt] = *(const s8*)&Bls[cn + nt * 16 + l16][quad * 8];
            #pragma unroll
            for (int mt = 0; mt < 2; ++mt)
                #pragma unroll
                for (int nt = 0; nt < 4; ++nt)
                    acc[mt][nt] = __builtin_amdgcn_mfma_f32_16x16x32_bf16(
                        af[mt], bfr[nt], acc[mt][nt], 0, 0, 0);
        }
    }

    // epilogue: C/D layout col=lane&15, row=quad*4+reg  (m89/m91-verified)
    #pragma unroll
    for (int mt = 0; mt < 2; ++mt) {
        #pragma unroll
        for (int nt = 0; nt < 4; ++nt) {
            int col = cn + nt * 16 + l16;
            float b = bias[col];
            #pragma unroll
            for (int r = 0; r < 4; ++r) {
                int row = row0 + rm + mt * 16 + quad * 4 + r;
                if (row < M)
                    out[(size_t)row * 128 + col] = acc[mt][nt][r] + b;
            }
        }
    }
}

// ---------------------------------------------------------------------------
// BatchNorm
// ---------------------------------------------------------------------------
__global__ void stats_kernel(const float* __restrict__ h, float* __restrict__ stats, int M) {
    __shared__ float l1[256], l2[256];
    int t = threadIdx.x;
    int f = t & 127;
    int part = t >> 7;
    float s1 = 0.f, s2 = 0.f;
    for (int n = blockIdx.x * 2 + part; n < M; n += gridDim.x * 2) {
        float v = h[(size_t)n * 128 + f];
        s1 += v;
        s2 = fmaf(v, v, s2);
    }
    l1[t] = s1; l2[t] = s2;
    __syncthreads();
    if (t < 128) {
        atomicAdd(&stats[f], l1[t] + l1[t + 128]);
        atomicAdd(&stats[128 + f], l2[t] + l2[t + 128]);
    }
}

__global__ void finalize_kernel(const float* __restrict__ stats,
                                const float* __restrict__ gamma,
                                const float* __restrict__ beta,
                                float* __restrict__ ss, float inv_n) {
    int t = threadIdx.x;  // 128
    float mean = stats[t] * inv_n;
    float var = stats[128 + t] * inv_n - mean * mean;
    float inv = 1.0f / sqrtf(var + BN_EPS);
    float sc = gamma[t] * inv;
    ss[t] = sc;
    ss[128 + t] = beta[t] - mean * sc;
}

// BN + ReLU + cast to bf16 (layer-0 -> layer-1 handoff)
__global__ void bn_relu_cast_kernel(const float* __restrict__ h, const float* __restrict__ ss,
                                    u16* __restrict__ hb, int total4) {
    int i = blockIdx.x * blockDim.x + threadIdx.x;
    if (i >= total4) return;
    int cg = i & 31;
    float4 v = ((const float4*)h)[i];
    float4 sc = *(const float4*)&ss[cg * 4];
    float4 sh = *(const float4*)&ss[128 + cg * 4];
    float r0 = fmaxf(fmaf(v.x, sc.x, sh.x), 0.f);
    float r1 = fmaxf(fmaf(v.y, sc.y, sh.y), 0.f);
    float r2 = fmaxf(fmaf(v.z, sc.z, sh.z), 0.f);
    float r3 = fmaxf(fmaf(v.w, sc.w, sh.w), 0.f);
    uint2 o;
    o.x = (uint)f2bf(r0) | ((uint)f2bf(r1) << 16);
    o.y = (uint)f2bf(r2) | ((uint)f2bf(r3) << 16);
    ((uint2*)hb)[i] = o;
}

// final BN, fp32 in-place on d_out
__global__ void bn_apply_kernel(float* __restrict__ h, const float* __restrict__ ss, int total4) {
    int i = blockIdx.x * blockDim.x + threadIdx.x;
    if (i >= total4) return;
    int cg = i & 31;
    float4 v = ((float4*)h)[i];
    float4 sc = *(const float4*)&ss[cg * 4];
    float4 sh = *(const float4*)&ss[128 + cg * 4];
    v.x = fmaf(v.x, sc.x, sh.x);
    v.y = fmaf(v.y, sc.y, sh.y);
    v.z = fmaf(v.z, sc.z, sh.z);
    v.w = fmaf(v.w, sc.w, sh.w);
    ((float4*)h)[i] = v;
}

// ---------------------------------------------------------------------------
extern "C" void kernel_launch(void* const* d_in, const int* in_sizes, int n_in,
                              void* d_out, int out_size, void* d_ws, size_t ws_size,
                              hipStream_t stream) {
    const float* x      = (const float*)d_in[0];
    const int*   ei     = (const int*)d_in[1];
    const float* W_l0   = (const float*)d_in[2];
    const float* b_l0   = (const float*)d_in[3];
    const float* W_r0   = (const float*)d_in[4];
    const float* gamma0 = (const float*)d_in[5];
    const float* beta0  = (const float*)d_in[6];
    const float* W_l1   = (const float*)d_in[7];
    const float* b_l1   = (const float*)d_in[8];
    const float* W_r1   = (const float*)d_in[9];
    const float* gamma1 = (const float*)d_in[10];
    const float* beta1  = (const float*)d_in[11];

    const int* src = ei;
    const int* dst = ei + N_EDGES;

    char* w = (char*)d_ws;
    auto alloc = [&](size_t bytes) {
        void* p = (void*)w;
        w += (bytes + 255) & ~(size_t)255;
        return p;
    };
    int* deg       = (int*)alloc(sizeof(int) * N_NODES);
    int* row_start = (int*)alloc(sizeof(int) * (N_NODES + 1));
    int* cursor    = (int*)alloc(sizeof(int) * N_NODES);
    int* ssrc      = (int*)alloc(sizeof(int) * N_EDGES);
    u16* xb        = (u16*)alloc(sizeof(u16) * (size_t)NPAD * 128);
    u16* hb        = (u16*)alloc(sizeof(u16) * (size_t)NPAD * 128);
    u16* aggb      = (u16*)alloc(sizeof(u16) * (size_t)NPAD * 128);
    u16* Wt        = (u16*)alloc(sizeof(u16) * 4 * 16384);
    float* stats0  = (float*)alloc(sizeof(float) * 256);
    float* ss0     = (float*)alloc(sizeof(float) * 256);
    float* stats1  = (float*)alloc(sizeof(float) * 256);
    float* ss1     = (float*)alloc(sizeof(float) * 256);
    float* outp    = (float*)d_out;   // also fp32 scratch for layer-0 pre-BN

    hipMemsetAsync(deg, 0, sizeof(int) * N_NODES, stream);
    hipMemsetAsync(stats0, 0, sizeof(float) * 256, stream);
    hipMemsetAsync(stats1, 0, sizeof(float) * 256, stream);

    const int EB = (N_EDGES + 255) / 256;
    const float inv_n = 1.0f / (float)N_NODES;
    const int total4 = N_NODES * HID / 4;
    const int GB = NPAD / 64;   // 782 GEMM blocks

    // CSR build + casts
    hist_kernel<<<EB, 256, 0, stream>>>(dst, deg);
    scan_kernel<<<1, 1024, 0, stream>>>(deg, row_start, cursor, N_NODES);
    fill_kernel<<<EB, 256, 0, stream>>>(src, dst, cursor, ssrc);
    cast_x_kernel<<<(N_NODES * 128 + 255) / 256, 256, 0, stream>>>(x, xb);
    cast_w_kernel<<<dim3(64, 4), 256, 0, stream>>>(W_l0, W_r0, W_l1, W_r1, Wt);

    // Layer 0
    agg_bf16<<<(N_NODES + 3) / 4, 256, 0, stream>>>(ssrc, row_start, xb, aggb);
    gemm_mfma<<<GB, 256, 0, stream>>>(aggb, xb, Wt, Wt + 16384, b_l0, outp, N_NODES);
    stats_kernel<<<256, 256, 0, stream>>>(outp, stats0, N_NODES);
    finalize_kernel<<<1, 128, 0, stream>>>(stats0, gamma0, beta0, ss0, inv_n);
    bn_relu_cast_kernel<<<(total4 + 255) / 256, 256, 0, stream>>>(outp, ss0, hb, total4);

    // Layer 1
    agg_bf16<<<(N_NODES + 3) / 4, 256, 0, stream>>>(ssrc, row_start, hb, aggb);
    gemm_mfma<<<GB, 256, 0, stream>>>(aggb, hb, Wt + 2 * 16384, Wt + 3 * 16384, b_l1, outp, N_NODES);
    stats_kernel<<<256, 256, 0, stream>>>(outp, stats1, N_NODES);
    finalize_kernel<<<1, 128, 0, stream>>>(stats1, gamma1, beta1, ss1, inv_n);
    bn_apply_kernel<<<(total4 + 255) / 256, 256, 0, stream>>>(outp, ss1, total4);
}

// Round 3
// 345.458 us; speedup vs baseline: 1.6071x; 1.2561x over previous
//
#include <hip/hip_runtime.h>
#include <hip/hip_bf16.h>

#define N_NODES 50000
#define N_EDGES 800000
#define NPAD    50048          // 782 * 64, so GEMM A-staging never reads OOB
#define IN_DIM  100
#define HID     128
#define BN_EPS  1e-5f

typedef unsigned int uint;
typedef unsigned short u16;
typedef __attribute__((ext_vector_type(8))) unsigned short us8;
typedef __attribute__((ext_vector_type(8))) short s8;      // bf16 MFMA frag
typedef __attribute__((ext_vector_type(4))) float f4;

__device__ __forceinline__ u16 f2bf(float f) {
    uint u = __builtin_bit_cast(uint, f);
    uint r = (u + 0x7FFFu + ((u >> 16) & 1u)) >> 16;   // RNE
    return (u16)r;
}
__device__ __forceinline__ uint pack2(float a, float b) {
    return (uint)f2bf(a) | ((uint)f2bf(b) << 16);
}
__device__ __forceinline__ float bflo(uint p) { return __builtin_bit_cast(float, p << 16); }
__device__ __forceinline__ float bfhi(uint p) { return __builtin_bit_cast(float, p & 0xFFFF0000u); }

// ---------------------------------------------------------------------------
// CSR build: histogram -> 3-stage scan -> fill
// ---------------------------------------------------------------------------
__global__ void hist_kernel(const int* __restrict__ dst, int* __restrict__ deg) {
    int e = blockIdx.x * blockDim.x + threadIdx.x;
    if (e < N_EDGES) atomicAdd(&deg[dst[e]], 1);
}

// per-block exclusive scan of 256 degs -> row_start (block-local), block total -> bsum
__global__ void scan_local(const int* __restrict__ deg, int* __restrict__ row_start,
                           int* __restrict__ bsum, int n) {
    __shared__ int ws[4];
    int t = threadIdx.x, lane = t & 63, wv = t >> 6;
    int i = blockIdx.x * 256 + t;
    int v = (i < n) ? deg[i] : 0;
    int s = v;
    #pragma unroll
    for (int off = 1; off < 64; off <<= 1) {
        int u = __shfl_up(s, off, 64);
        if (lane >= off) s += u;
    }
    if (lane == 63) ws[wv] = s;
    __syncthreads();
    int woff = 0;
    #pragma unroll
    for (int j = 0; j < 4; j++) if (j < wv) woff += ws[j];
    if (i < n) row_start[i] = s - v + woff;
    if (t == 0) bsum[blockIdx.x] = ws[0] + ws[1] + ws[2] + ws[3];
}

// single block: exclusive scan of nb (<=256) block sums in place
__global__ void scan_bsums(int* __restrict__ bsum, int nb) {
    __shared__ int ws[4];
    int t = threadIdx.x, lane = t & 63, wv = t >> 6;
    int v = (t < nb) ? bsum[t] : 0;
    int s = v;
    #pragma unroll
    for (int off = 1; off < 64; off <<= 1) {
        int u = __shfl_up(s, off, 64);
        if (lane >= off) s += u;
    }
    if (lane == 63) ws[wv] = s;
    __syncthreads();
    int woff = 0;
    #pragma unroll
    for (int j = 0; j < 4; j++) if (j < wv) woff += ws[j];
    if (t < nb) bsum[t] = s - v + woff;
}

// add block offsets; produce final row_start + cursor
__global__ void scan_apply(int* __restrict__ row_start, const int* __restrict__ bsum,
                           int* __restrict__ cursor, int n) {
    int i = blockIdx.x * 256 + threadIdx.x;
    if (i < n) {
        int v = row_start[i] + bsum[blockIdx.x];
        row_start[i] = v;
        cursor[i] = v;
    }
    if (i == 0) row_start[n] = N_EDGES;
}

__global__ void fill_kernel(const int* __restrict__ src, const int* __restrict__ dst,
                            int* __restrict__ cursor, int* __restrict__ ssrc) {
    int e = blockIdx.x * blockDim.x + threadIdx.x;
    if (e < N_EDGES) {
        int pos = atomicAdd(&cursor[dst[e]], 1);
        ssrc[pos] = src[e];
    }
}

// ---------------------------------------------------------------------------
// Casts to bf16
// ---------------------------------------------------------------------------
__global__ void cast_x_kernel(const float* __restrict__ x, u16* __restrict__ xb) {
    int idx = blockIdx.x * blockDim.x + threadIdx.x;
    if (idx >= N_NODES * 128) return;
    int row = idx >> 7, k = idx & 127;
    float v = (k < IN_DIM) ? x[row * IN_DIM + k] : 0.f;
    xb[idx] = f2bf(v);
}

// weights: fp32 [Ksrc][128] -> bf16 transposed [128 n][128 k], zero-padded k
__global__ void cast_w_kernel(const float* __restrict__ W_l0, const float* __restrict__ W_r0,
                              const float* __restrict__ W_l1, const float* __restrict__ W_r1,
                              u16* __restrict__ d) {
    int w = blockIdx.y;
    const float* s = (w == 0) ? W_l0 : (w == 1) ? W_r0 : (w == 2) ? W_l1 : W_r1;
    int Ks = (w < 2) ? IN_DIM : HID;
    int idx = blockIdx.x * 256 + threadIdx.x;   // 0..16383
    int n = idx >> 7, k = idx & 127;
    float v = (k < Ks) ? s[k * 128 + n] : 0.f;
    d[w * 16384 + idx] = f2bf(v);
}

// ---------------------------------------------------------------------------
// Mean aggregation v2: one wave per node, quad q handles edge e+q,
// lanes 0..15 of each quad load a full row via uint4 (16B/lane).
// ---------------------------------------------------------------------------
__global__ void agg_bf16(const int* __restrict__ ssrc, const int* __restrict__ rs,
                         const u16* __restrict__ X, u16* __restrict__ out) {
    int node = (blockIdx.x * blockDim.x + threadIdx.x) >> 6;
    if (node >= N_NODES) return;
    int lane = threadIdx.x & 63;
    int quad = lane >> 4, sub = lane & 15;
    int beg = rs[node], end = rs[node + 1];

    float a0 = 0.f, a1 = 0.f, a2 = 0.f, a3 = 0.f;
    float a4 = 0.f, a5 = 0.f, a6 = 0.f, a7 = 0.f;

    int e = beg;
    // main loop: 8 edges per iteration, two independent 16B loads per lane
    for (; e + 8 <= end; e += 8) {
        int s0 = ssrc[e + quad];
        int s1 = ssrc[e + 4 + quad];
        uint4 v0 = ((const uint4*)(X + (size_t)s0 * 128))[sub];
        uint4 v1 = ((const uint4*)(X + (size_t)s1 * 128))[sub];
        a0 += bflo(v0.x) + bflo(v1.x);
        a1 += bfhi(v0.x) + bfhi(v1.x);
        a2 += bflo(v0.y) + bflo(v1.y);
        a3 += bfhi(v0.y) + bfhi(v1.y);
        a4 += bflo(v0.z) + bflo(v1.z);
        a5 += bfhi(v0.z) + bfhi(v1.z);
        a6 += bflo(v0.w) + bflo(v1.w);
        a7 += bfhi(v0.w) + bfhi(v1.w);
    }
    // tail: 4 edges at a time, quad-masked
    for (; e < end; e += 4) {
        int ee = e + quad;
        if (ee < end) {
            int s0 = ssrc[ee];
            uint4 v0 = ((const uint4*)(X + (size_t)s0 * 128))[sub];
            a0 += bflo(v0.x); a1 += bfhi(v0.x);
            a2 += bflo(v0.y); a3 += bfhi(v0.y);
            a4 += bflo(v0.z); a5 += bfhi(v0.z);
            a6 += bflo(v0.w); a7 += bfhi(v0.w);
        }
    }
    // cross-quad reduction (features are identical across quads)
    #pragma unroll
    for (int m = 16; m <= 32; m <<= 1) {
        a0 += __shfl_xor(a0, m, 64); a1 += __shfl_xor(a1, m, 64);
        a2 += __shfl_xor(a2, m, 64); a3 += __shfl_xor(a3, m, 64);
        a4 += __shfl_xor(a4, m, 64); a5 += __shfl_xor(a5, m, 64);
        a6 += __shfl_xor(a6, m, 64); a7 += __shfl_xor(a7, m, 64);
    }
    if (quad == 0) {
        float inv = 1.0f / fmaxf((float)(end - beg), 1.0f);
        uint4 o;
        o.x = pack2(a0 * inv, a1 * inv);
        o.y = pack2(a2 * inv, a3 * inv);
        o.z = pack2(a4 * inv, a5 * inv);
        o.w = pack2(a6 * inv, a7 * inv);
        ((uint4*)(out + (size_t)node * 128))[sub] = o;
    }
}

// ---------------------------------------------------------------------------
// Dual-input bf16 MFMA GEMM (unchanged from round 2; passed + fast)
// ---------------------------------------------------------------------------
__global__ __launch_bounds__(256) void gemm_mfma(
    const u16* __restrict__ A1, const u16* __restrict__ A2,
    const u16* __restrict__ Wt1, const u16* __restrict__ Wt2,
    const float* __restrict__ bias, float* __restrict__ out, int M) {
    __shared__ u16 Als[64][32];
    __shared__ u16 Bls[128][32];

    int tid = threadIdx.x;
    int wave = tid >> 6;
    int lane = tid & 63;
    int l16 = lane & 15;
    int quad = lane >> 4;
    int rm = (wave & 1) * 32;
    int cn = (wave >> 1) * 64;
    int row0 = blockIdx.x * 64;

    f4 acc[2][4];
    #pragma unroll
    for (int i = 0; i < 2; i++)
        #pragma unroll
        for (int j = 0; j < 4; j++)
            acc[i][j] = (f4)0.f;

    #pragma unroll
    for (int phase = 0; phase < 2; ++phase) {
        const u16* A  = phase ? A2 : A1;
        const u16* Wt = phase ? Wt2 : Wt1;
        #pragma unroll
        for (int k0 = 0; k0 < 128; k0 += 32) {
            __syncthreads();
            {
                int r = tid >> 2, c = tid & 3;
                us8 v = *(const us8*)(A + (size_t)(row0 + r) * 128 + k0 + c * 8);
                *(us8*)&Als[r][c * 8] = v;
            }
            #pragma unroll
            for (int rep = 0; rep < 2; ++rep) {
                int idx = rep * 256 + tid;
                int n = idx >> 2, c = idx & 3;
                us8 v = *(const us8*)(Wt + n * 128 + k0 + c * 8);
                *(us8*)&Bls[n][c * 8] = v;
            }
            __syncthreads();
            s8 af[2], bfr[4];
            #pragma unroll
            for (int mt = 0; mt < 2; ++mt)
                af[mt] = *(const s8*)&Als[rm + mt * 16 + l16][quad * 8];
            #pragma unroll
            for (int nt = 0; nt < 4; ++nt)
                bfr[nt] = *(const s8*)&Bls[cn + nt * 16 + l16][quad * 8];
            #pragma unroll
            for (int mt = 0; mt < 2; ++mt)
                #pragma unroll
                for (int nt = 0; nt < 4; ++nt)
                    acc[mt][nt] = __builtin_amdgcn_mfma_f32_16x16x32_bf16(
                        af[mt], bfr[nt], acc[mt][nt], 0, 0, 0);
        }
    }

    #pragma unroll
    for (int mt = 0; mt < 2; ++mt) {
        #pragma unroll
        for (int nt = 0; nt < 4; ++nt) {
            int col = cn + nt * 16 + l16;
            float b = bias[col];
            #pragma unroll
            for (int r = 0; r < 4; ++r) {
                int row = row0 + rm + mt * 16 + quad * 4 + r;
                if (row < M)
                    out[(size_t)row * 128 + col] = acc[mt][nt][r] + b;
            }
        }
    }
}

// ---------------------------------------------------------------------------
// BatchNorm stats: float4 reads, LDS tree, 8 atomics per block
// ---------------------------------------------------------------------------
__global__ void stats_kernel(const float* __restrict__ h, float* __restrict__ stats, int M) {
    __shared__ float l1[256 * 4], l2[256 * 4];
    int t = threadIdx.x;             // 256
    int tg = t >> 5, c = t & 31;     // 8 row-groups x 32 float4-cols
    float s1x = 0.f, s1y = 0.f, s1z = 0.f, s1w = 0.f;
    float s2x = 0.f, s2y = 0.f, s2z = 0.f, s2w = 0.f;
    for (int n = blockIdx.x * 8 + tg; n < M; n += gridDim.x * 8) {
        float4 v = ((const float4*)(h + (size_t)n * 128))[c];
        s1x += v.x; s1y += v.y; s1z += v.z; s1w += v.w;
        s2x = fmaf(v.x, v.x, s2x); s2y = fmaf(v.y, v.y, s2y);
        s2z = fmaf(v.z, v.z, s2z); s2w = fmaf(v.w, v.w, s2w);
    }
    l1[t * 4 + 0] = s1x; l1[t * 4 + 1] = s1y; l1[t * 4 + 2] = s1z; l1[t * 4 + 3] = s1w;
    l2[t * 4 + 0] = s2x; l2[t * 4 + 1] = s2y; l2[t * 4 + 2] = s2z; l2[t * 4 + 3] = s2w;
    __syncthreads();
    #pragma unroll
    for (int stride = 128; stride >= 64; stride >>= 1) {
        if (t < stride) {
            #pragma unroll
            for (int j = 0; j < 4; j++) {
                l1[t * 4 + j] += l1[(t + stride) * 4 + j];
                l2[t * 4 + j] += l2[(t + stride) * 4 + j];
            }
        }
        __syncthreads();
    }
    if (t < 32) {
        #pragma unroll
        for (int j = 0; j < 4; j++) {
            float v1 = l1[t * 4 + j] + l1[(t + 32) * 4 + j];
            float v2 = l2[t * 4 + j] + l2[(t + 32) * 4 + j];
            atomicAdd(&stats[t * 4 + j], v1);
            atomicAdd(&stats[128 + t * 4 + j], v2);
        }
    }
}

// BN(+ReLU)+cast to bf16, finalize inlined (layer-0 -> layer-1 handoff)
__global__ void bn_relu_cast_kernel(const float* __restrict__ h,
                                    const float* __restrict__ stats,
                                    const float* __restrict__ gamma,
                                    const float* __restrict__ beta,
                                    u16* __restrict__ hb, float inv_n, int total4) {
    __shared__ float ss[256];
    int t = threadIdx.x;
    if (t < 128) {
        float mean = stats[t] * inv_n;
        float var = stats[128 + t] * inv_n - mean * mean;
        float inv = 1.0f / sqrtf(var + BN_EPS);
        float sc = gamma[t] * inv;
        ss[t] = sc;
        ss[128 + t] = beta[t] - mean * sc;
    }
    __syncthreads();
    for (int i = blockIdx.x * 256 + t; i < total4; i += gridDim.x * 256) {
        int cg = i & 31;
        float4 v = ((const float4*)h)[i];
        float4 sc = *(const float4*)&ss[cg * 4];
        float4 sh = *(const float4*)&ss[128 + cg * 4];
        float r0 = fmaxf(fmaf(v.x, sc.x, sh.x), 0.f);
        float r1 = fmaxf(fmaf(v.y, sc.y, sh.y), 0.f);
        float r2 = fmaxf(fmaf(v.z, sc.z, sh.z), 0.f);
        float r3 = fmaxf(fmaf(v.w, sc.w, sh.w), 0.f);
        uint2 o;
        o.x = pack2(r0, r1);
        o.y = pack2(r2, r3);
        ((uint2*)hb)[i] = o;
    }
}

// final BN, fp32 in-place on d_out, finalize inlined
__global__ void bn_apply_kernel(float* __restrict__ h,
                                const float* __restrict__ stats,
                                const float* __restrict__ gamma,
                                const float* __restrict__ beta,
                                float inv_n, int total4) {
    __shared__ float ss[256];
    int t = threadIdx.x;
    if (t < 128) {
        float mean = stats[t] * inv_n;
        float var = stats[128 + t] * inv_n - mean * mean;
        float inv = 1.0f / sqrtf(var + BN_EPS);
        float sc = gamma[t] * inv;
        ss[t] = sc;
        ss[128 + t] = beta[t] - mean * sc;
    }
    __syncthreads();
    for (int i = blockIdx.x * 256 + t; i < total4; i += gridDim.x * 256) {
        int cg = i & 31;
        float4 v = ((float4*)h)[i];
        float4 sc = *(const float4*)&ss[cg * 4];
        float4 sh = *(const float4*)&ss[128 + cg * 4];
        v.x = fmaf(v.x, sc.x, sh.x);
        v.y = fmaf(v.y, sc.y, sh.y);
        v.z = fmaf(v.z, sc.z, sh.z);
        v.w = fmaf(v.w, sc.w, sh.w);
        ((float4*)h)[i] = v;
    }
}

// ---------------------------------------------------------------------------
extern "C" void kernel_launch(void* const* d_in, const int* in_sizes, int n_in,
                              void* d_out, int out_size, void* d_ws, size_t ws_size,
                              hipStream_t stream) {
    const float* x      = (const float*)d_in[0];
    const int*   ei     = (const int*)d_in[1];
    const float* W_l0   = (const float*)d_in[2];
    const float* b_l0   = (const float*)d_in[3];
    const float* W_r0   = (const float*)d_in[4];
    const float* gamma0 = (const float*)d_in[5];
    const float* beta0  = (const float*)d_in[6];
    const float* W_l1   = (const float*)d_in[7];
    const float* b_l1   = (const float*)d_in[8];
    const float* W_r1   = (const float*)d_in[9];
    const float* gamma1 = (const float*)d_in[10];
    const float* beta1  = (const float*)d_in[11];

    const int* src = ei;
    const int* dst = ei + N_EDGES;

    char* w = (char*)d_ws;
    auto alloc = [&](size_t bytes) {
        void* p = (void*)w;
        w += (bytes + 255) & ~(size_t)255;
        return p;
    };
    // zero-init span: stats0, stats1, deg allocated contiguously
    char* zbase    = w;
    float* stats0  = (float*)alloc(sizeof(float) * 256);
    float* stats1  = (float*)alloc(sizeof(float) * 256);
    int* deg       = (int*)alloc(sizeof(int) * N_NODES);
    size_t zbytes  = (size_t)(w - zbase);

    int* row_start = (int*)alloc(sizeof(int) * (N_NODES + 1));
    int* cursor    = (int*)alloc(sizeof(int) * N_NODES);
    int* bsum      = (int*)alloc(sizeof(int) * 256);
    int* ssrc      = (int*)alloc(sizeof(int) * N_EDGES);
    u16* xb        = (u16*)alloc(sizeof(u16) * (size_t)NPAD * 128);
    u16* hb        = (u16*)alloc(sizeof(u16) * (size_t)NPAD * 128);
    u16* aggb      = (u16*)alloc(sizeof(u16) * (size_t)NPAD * 128);
    u16* Wt        = (u16*)alloc(sizeof(u16) * 4 * 16384);
    float* outp    = (float*)d_out;   // fp32 scratch for layer-0 pre-BN

    hipMemsetAsync(zbase, 0, zbytes, stream);

    const int EB = (N_EDGES + 255) / 256;
    const int NB = (N_NODES + 255) / 256;   // 196
    const float inv_n = 1.0f / (float)N_NODES;
    const int total4 = N_NODES * HID / 4;
    const int GB = NPAD / 64;

    // CSR build + casts
    hist_kernel<<<EB, 256, 0, stream>>>(dst, deg);
    scan_local<<<NB, 256, 0, stream>>>(deg, row_start, bsum, N_NODES);
    scan_bsums<<<1, 256, 0, stream>>>(bsum, NB);
    scan_apply<<<NB, 256, 0, stream>>>(row_start, bsum, cursor, N_NODES);
    fill_kernel<<<EB, 256, 0, stream>>>(src, dst, cursor, ssrc);
    cast_x_kernel<<<(N_NODES * 128 + 255) / 256, 256, 0, stream>>>(x, xb);
    cast_w_kernel<<<dim3(64, 4), 256, 0, stream>>>(W_l0, W_r0, W_l1, W_r1, Wt);

    // Layer 0
    agg_bf16<<<(N_NODES + 3) / 4, 256, 0, stream>>>(ssrc, row_start, xb, aggb);
    gemm_mfma<<<GB, 256, 0, stream>>>(aggb, xb, Wt, Wt + 16384, b_l0, outp, N_NODES);
    stats_kernel<<<128, 256, 0, stream>>>(outp, stats0, N_NODES);
    bn_relu_cast_kernel<<<2048, 256, 0, stream>>>(outp, stats0, gamma0, beta0, hb, inv_n, total4);

    // Layer 1
    agg_bf16<<<(N_NODES + 3) / 4, 256, 0, stream>>>(ssrc, row_start, hb, aggb);
    gemm_mfma<<<GB, 256, 0, stream>>>(aggb, hb, Wt + 2 * 16384, Wt + 3 * 16384, b_l1, outp, N_NODES);
    stats_kernel<<<128, 256, 0, stream>>>(outp, stats1, N_NODES);
    bn_apply_kernel<<<2048, 256, 0, stream>>>(outp, stats1, gamma1, beta1, inv_n, total4);
}